// Round 20
// baseline (494.095 us; speedup 1.0000x reference)
//
#include <hip/hip_runtime.h>

#define BB 8
#define TT 4096
#define DD 768
#define MM (BB*TT)   // 32768

typedef _Float16 f16;
typedef _Float16 f16x8 __attribute__((ext_vector_type(8)));
typedef float f32x4 __attribute__((ext_vector_type(4)));

typedef __attribute__((address_space(1))) void void_g;
typedef __attribute__((address_space(3))) void void_l;

// async global->LDS, 16B per lane. LDS dest = wave-uniform base + lane*16 (linear).
__device__ __forceinline__ void gload16(const void* g, void* l) {
  __builtin_amdgcn_global_load_lds((void_g*)g, (void_l*)l, 16, 0, 0);
}

// ---------------- both weight matrices f32 -> f16, one launch -------------
__global__ void cvt2_f32_f16(const float* __restrict__ a, const float* __restrict__ b,
                             f16* __restrict__ oa, f16* __restrict__ ob, int n) {
  int i = (blockIdx.x * blockDim.x + threadIdx.x) * 8;
  if (i >= 2 * n) return;
  const float* src = (i < n) ? a : b;
  f16* dst = (i < n) ? oa : ob;
  const int j = (i < n) ? i : i - n;
  float4 x = *(const float4*)(src + j);
  float4 y = *(const float4*)(src + j + 4);
  f16x8 o;
  o[0] = (f16)x.x; o[1] = (f16)x.y; o[2] = (f16)x.z; o[3] = (f16)x.w;
  o[4] = (f16)y.x; o[5] = (f16)y.y; o[6] = (f16)y.z; o[7] = (f16)y.w;
  *(f16x8*)(dst + j) = o;
}

// ---------------- fused proj dispatch: z=0 -> Q (frag layout), z=1 -> K ----
// Tile 64m x 256n (grid 512 x 3 x 2), 4 waves (1m x 4n), double-buffered.
// Q path also writes Xh (f16 X) when n0==0. Qf fragment layout:
// idx = (((row>>6)*24 + (col>>5))*4 + ((row>>4)&3))*512
//       + ((row&15) + ((col>>3)&3)*16)*8 + (col&7)
__global__ __launch_bounds__(256, 3)
void proj_qk(const float* __restrict__ Af,
             const f16* __restrict__ Wqh, const f16* __restrict__ Wkh,
             const float* __restrict__ bq, const float* __restrict__ bk,
             f16* __restrict__ Qf, f16* __restrict__ Kh,
             f16* __restrict__ Xout) {
  __shared__ f16 As[2][64 * 32];
  __shared__ f16 Ws[2][256 * 32];
  const int isK = blockIdx.z;
  const f16* Wh = isK ? Wkh : Wqh;
  const float* bias = isK ? bk : bq;
  const int m0 = blockIdx.x * 64;
  const int n0 = blockIdx.y * 256;
  const int t = threadIdx.x;
  const int lane = t & 63;
  const int w = t >> 6;
  const int wn = w * 64;
  const int fr = lane & 15, fq = lane >> 4;
  const int xst = ((t >> 3) & 3) << 3;
  const int xrd = ((fr >> 1) & 3) << 3;

  f32x4 acc[4][4] = {};

  const int r0 = t >> 2, cA = (t & 3) * 8;
  const int e0 = t * 8;
  const int c8 = ((t & 3) ^ ((t >> 3) & 3)) * 8;
  const f16* w0 = Wh + (size_t)(n0 + r0) * DD + c8;
  const bool wout = (Xout != nullptr) && (!isK) && (n0 == 0);

#define PSTAGE(bf, ks_) do { \
    const int k0_ = (ks_) * 32; \
    gload16(w0 + k0_,                      &Ws[bf][w * 512]); \
    gload16(w0 + (size_t)64  * DD + k0_,   &Ws[bf][2048 + w * 512]); \
    gload16(w0 + (size_t)128 * DD + k0_,   &Ws[bf][4096 + w * 512]); \
    gload16(w0 + (size_t)192 * DD + k0_,   &Ws[bf][6144 + w * 512]); \
    { \
      const float* g0 = Af + (size_t)(m0 + r0) * DD + k0_ + cA; \
      float4 x0 = *(const float4*)g0, x1 = *(const float4*)(g0 + 4); \
      f16x8 va; \
      va[0] = (f16)x0.x; va[1] = (f16)x0.y; va[2] = (f16)x0.z; va[3] = (f16)x0.w; \
      va[4] = (f16)x1.x; va[5] = (f16)x1.y; va[6] = (f16)x1.z; va[7] = (f16)x1.w; \
      *(f16x8*)&As[bf][e0 ^ xst] = va; \
      if (wout) *(f16x8*)&Xout[(size_t)(m0 + r0) * DD + k0_ + cA] = va; \
    } \
  } while (0)

  PSTAGE(0, 0);
  __syncthreads();

  for (int ks = 0; ks < 24; ++ks) {
    const int bf = ks & 1;
    if (ks + 1 < 24) PSTAGE(bf ^ 1, ks + 1);
    f16x8 a[4], b[4];
#pragma unroll
    for (int i = 0; i < 4; ++i)
      a[i] = *(const f16x8*)&As[bf][(((i * 16 + fr) * 32) + fq * 8) ^ xrd];
#pragma unroll
    for (int j = 0; j < 4; ++j)
      b[j] = *(const f16x8*)&Ws[bf][(((wn + j * 16 + fr) * 32) + fq * 8) ^ xrd];
#pragma unroll
    for (int i = 0; i < 4; ++i)
#pragma unroll
      for (int j = 0; j < 4; ++j)
        acc[i][j] = __builtin_amdgcn_mfma_f32_16x16x32_f16(a[i], b[j], acc[i][j], 0, 0, 0);
    __syncthreads();
  }
#undef PSTAGE

#pragma unroll
  for (int j = 0; j < 4; ++j) {
    const int col = n0 + wn + j * 16 + fr;
    const float bv = bias[col];
#pragma unroll
    for (int i = 0; i < 4; ++i) {
#pragma unroll
      for (int r = 0; r < 4; ++r) {
        const int row = m0 + i * 16 + fq * 4 + r;
        const f16 v = (f16)(acc[i][j][r] + bv);
        if (!isK) {
          const size_t idx = (((size_t)(row >> 6) * 24 + (col >> 5)) * 4 +
                              ((row >> 4) & 3)) * 512 +
                             ((row & 15) + (((col >> 3) & 3) << 4)) * 8 + (col & 7);
          Qf[idx] = v;
        } else {
          Kh[(size_t)row * DD + col] = v;
        }
      }
    }
  }
}

// ---------------- attn16: BARRIER-FREE wave-private pipeline --------------
// Each wave stages its OWN 64x32 K chunk into a private LDS dbuf region
// (4 gload16 -> 4KB; 32KB/block total) and reads only its own region.
// Zero __syncthreads in the kernel: waves drift freely, per-wave vmcnt(0)
// at step end orders own gload_lds -> ds_read. Cost: K staged per-wave
// (2x L2 reads of K). Math/layout identical to attn15 (no-max Z).
// (256,3); ~150 total regs (incl 64 AGPR) <= 170 (tripwire: WRITE_SIZE).
// Grid 768: bid = qs*24 + kh*8 + bb; kh thirds kt {11,11,10}; H = cnt*24.
__global__ __launch_bounds__(256, 3)
void attn16(const f16* __restrict__ Qf, const f16* __restrict__ K,
            const int* __restrict__ mask, float* __restrict__ pzv,
            float* __restrict__ sdg) {
  __shared__ f16 Ks[4][2][64 * 32];   // [wave][buf][4KB]

  const int bid = blockIdx.x;
  const int qs = bid / 24;
  const int kh = (bid % 24) >> 3;
  const int bb = bid & 7;
  const int t = threadIdx.x, l = t & 63, w = t >> 6;
  const int wq = w >> 1, wk = w & 1;
  const int fr = l & 15, fq = l >> 4;
  const int q0 = qs * 128;
  const float scale = 0.036084391824351613f;  // 1/sqrt(768)
  const int lo = kh * 11;
  const int cnt = (kh < 2) ? 11 : 10;
  const int H = cnt * 24;

  const f16* Kg = K + (size_t)bb * TT * DD;

  // Qf base: 64-row group grp = bb*64 + qs*2 + wq; lane offset l*8.
  const int grp = bb * 64 + qs * 2 + wq;
  const f16* qf = Qf + (size_t)grp * 24 * 4 * 512 + (size_t)l * 8;

  // per-wave K staging: 4 issues cover rows 16i+(l>>2) of the wave's own
  // 64-row half (wk*64+..); source col-slot pre-swizzled (^((row>>1)&3)
  // reduces to ^((l>>3)&3) for every 16-row issue).
  const int c8 = ((l & 3) ^ ((l >> 3) & 3)) * 8;
  const f16* kw = Kg + (size_t)(wk * 64 + (l >> 2)) * DD + c8;

  // fragment read within own region: (j*16+fr)*32 + sx
  const int sx = (fq ^ ((fr >> 1) & 3)) * 8;
  f16* lds0 = &Ks[w][0][0];
  f16* lds1 = &Ks[w][1][0];

  f32x4 acc[4][4] = {};
  f32x4 zacc[4] = {};
  int im0 = 1, im1 = 1, im2 = 1, im3 = 1;
  f16x8 avA[4], avB[4];

#define STAGE(dst, h_) do { \
    if ((h_) < H) { \
      const size_t o0 = (size_t)(lo + (h_) / 24) * 128 * DD + (size_t)(((h_) % 24) * 32); \
      gload16(kw + o0,                    (dst)); \
      gload16(kw + (size_t)16 * DD + o0,  (dst) + 512); \
      gload16(kw + (size_t)32 * DD + o0,  (dst) + 1024); \
      gload16(kw + (size_t)48 * DD + o0,  (dst) + 1536); \
    } \
  } while (0)

#define QLOAD(dst, dc_) do { \
    const f16* qp_ = qf + (size_t)(dc_) * 2048; \
    _Pragma("unroll") \
    for (int i = 0; i < 4; ++i) (dst)[i] = *(const f16x8*)(qp_ + i * 512); \
  } while (0)

#define MFMA_ALL(av_, lds_) do { \
    f16x8 bv[4]; \
    _Pragma("unroll") \
    for (int j = 0; j < 4; ++j) bv[j] = *(const f16x8*)&(lds_)[(j * 16 + fr) * 32 + sx]; \
    __builtin_amdgcn_s_setprio(1); \
    _Pragma("unroll") \
    for (int i = 0; i < 4; ++i) \
      _Pragma("unroll") \
      for (int j = 0; j < 4; ++j) \
        acc[i][j] = __builtin_amdgcn_mfma_f32_16x16x32_f16((av_)[i], bv[j], acc[i][j], 0, 0, 0); \
    __builtin_amdgcn_s_setprio(0); \
  } while (0)

// per-wave pipeline fence: own gload_lds complete before next ds_read
#define WAVE_FENCE() do { \
    __builtin_amdgcn_sched_barrier(0); \
    asm volatile("s_waitcnt vmcnt(0)" ::: "memory"); \
    __builtin_amdgcn_sched_barrier(0); \
  } while (0)

#define KT_EPILOGUE(kt_) do { \
    const float mb0 = im0 ? 0.f : -1e30f; \
    const float mb1 = im1 ? 0.f : -1e30f; \
    const float mb2 = im2 ? 0.f : -1e30f; \
    const float mb3 = im3 ? 0.f : -1e30f; \
    const bool isdiag = ((kt_) == qs); \
    _Pragma("unroll") \
    for (int i = 0; i < 4; ++i) { \
      _Pragma("unroll") \
      for (int rg = 0; rg < 4; ++rg) { \
        float v0 = fmaf(acc[i][0][rg], scale, mb0); \
        float v1 = fmaf(acc[i][1][rg], scale, mb1); \
        float v2 = fmaf(acc[i][2][rg], scale, mb2); \
        float v3 = fmaf(acc[i][3][rg], scale, mb3); \
        if (isdiag) { \
          const int rl = wq * 64 + i * 16 + fq * 4 + rg; \
          const int cl = wk * 64 + fr; \
          if (cl      == rl) sdg[(size_t)bb * TT + q0 + rl] = v0; \
          if (cl + 16 == rl) sdg[(size_t)bb * TT + q0 + rl] = v1; \
          if (cl + 32 == rl) sdg[(size_t)bb * TT + q0 + rl] = v2; \
          if (cl + 48 == rl) sdg[(size_t)bb * TT + q0 + rl] = v3; \
        } \
        zacc[i][rg] += __expf(v0) + __expf(v1) + __expf(v2) + __expf(v3); \
      } \
    } \
    _Pragma("unroll") \
    for (int i = 0; i < 4; ++i) \
      _Pragma("unroll") \
      for (int j = 0; j < 4; ++j) acc[i][j] = (f32x4)(0.f); \
  } while (0)

  // prologue: stage step 0 into buf0; prefetch avA(dc=0); fence.
  STAGE(lds0, 0);
  QLOAD(avA, 0);
  WAVE_FENCE();

  for (int h2 = 0; h2 < H; h2 += 2) {
    const int kt = lo + h2 / 24, dc = h2 % 24;   // dc even: 0,2,..,22
    if (dc == 0) {  // preload mask for this kt (consumed at dc==23, odd sub)
      const int kb = bb * TT + kt * 128 + wk * 64 + fr;
      im0 = mask[kb]; im1 = mask[kb + 16]; im2 = mask[kb + 32]; im3 = mask[kb + 48];
    }

    // ---- even h: stage(h2+1 -> buf1), prefetch avB(dc+1); MFMA(avA, buf0)
    STAGE(lds1, h2 + 1);
    QLOAD(avB, dc + 1);
    MFMA_ALL(avA, lds0);
    WAVE_FENCE();

    // ---- odd h: stage(h2+2 -> buf0), prefetch avA(next dc); MFMA(avB, buf1)
    STAGE(lds0, h2 + 2);
    if (h2 + 2 < H) QLOAD(avA, (h2 + 2) % 24);
    MFMA_ALL(avB, lds1);

    if (dc == 22) KT_EPILOGUE(kt);   // h2+1 has dc==23

    WAVE_FENCE();
  }
#undef STAGE
#undef QLOAD
#undef MFMA_ALL
#undef WAVE_FENCE
#undef KT_EPILOGUE

  // reduce zacc across the 16 fr-lanes; write per-(kh,wk) partial Z (6 slots)
  const int slot = kh * 2 + wk;
#pragma unroll
  for (int i = 0; i < 4; ++i) {
#pragma unroll
    for (int rg = 0; rg < 4; ++rg) {
      float z = zacc[i][rg];
#pragma unroll
      for (int off = 1; off < 16; off <<= 1) z += __shfl_xor(z, off);
      if (fr == 0) {
        const int row = wq * 64 + i * 16 + fq * 4 + rg;
        pzv[(size_t)slot * MM + bb * TT + q0 + row] = z;
      }
    }
  }
}

// ---------------- merge 6 partials -> wdiag (+ zero out) ----------------
__global__ void merge6(const float* __restrict__ pz, const float* __restrict__ sdg,
                       float* __restrict__ wdiag, float* __restrict__ out) {
  int i = blockIdx.x * 256 + threadIdx.x;
  if (i < BB * DD) out[i] = 0.f;
  if (i >= MM) return;
  float Z = 0.f;
#pragma unroll
  for (int s = 0; s < 6; ++s) Z += pz[(size_t)s * MM + i];
  wdiag[i] = __expf(sdg[i]) / Z;
}

// out[b,d] = sum_t X[b,t,d] * wdiag[b,t]  (f32 X fallback)
__global__ __launch_bounds__(256)
void out_gemv(const float* __restrict__ X, const float* __restrict__ wdiag,
              float* __restrict__ out) {
  __shared__ float wsm[256];
  const int b = blockIdx.z;
  const int d = blockIdx.y * 256 + threadIdx.x;
  const int tbase = blockIdx.x * 256;
  wsm[threadIdx.x] = wdiag[b * TT + tbase + threadIdx.x];
  __syncthreads();
  float acc = 0.f;
  const float* xp = X + (size_t)(b * TT + tbase) * DD + d;
#pragma unroll 4
  for (int i = 0; i < 256; ++i) acc += xp[(size_t)i * DD] * wsm[i];
  atomicAdd(&out[b * DD + d], acc);
}

// out[b,d] = sum_t Xh[b,t,d] * wdiag[b,t]  (f16 X, half the traffic)
__global__ __launch_bounds__(256)
void out_gemv_h(const f16* __restrict__ Xh, const float* __restrict__ wdiag,
                float* __restrict__ out) {
  __shared__ float wsm[256];
  const int b = blockIdx.z;
  const int d = blockIdx.y * 256 + threadIdx.x;
  const int tbase = blockIdx.x * 256;
  wsm[threadIdx.x] = wdiag[b * TT + tbase + threadIdx.x];
  __syncthreads();
  float acc = 0.f;
  const f16* xp = Xh + (size_t)(b * TT + tbase) * DD + d;
#pragma unroll 4
  for (int i = 0; i < 256; ++i) acc += (float)xp[(size_t)i * DD] * wsm[i];
  atomicAdd(&out[b * DD + d], acc);
}

extern "C" void kernel_launch(void* const* d_in, const int* in_sizes, int n_in,
                              void* d_out, int out_size, void* d_ws, size_t ws_size,
                              hipStream_t stream) {
  const float* X    = (const float*)d_in[0];
  const int*   mask = (const int*)d_in[1];
  const float* Wq_w = (const float*)d_in[2];
  const float* Wq_b = (const float*)d_in[3];
  const float* Wk_w = (const float*)d_in[4];
  const float* Wk_b = (const float*)d_in[5];
  float* out = (float*)d_out;

  const size_t n2 = (size_t)MM * DD;              // 25.17M f16 elems
  const size_t wreg = 2 * (size_t)DD * DD;
  const size_t need_full = (3 * n2 + wreg) * sizeof(f16);  // ~153.4 MB
  const bool useXh = ws_size >= need_full;

  f16* Qf  = (f16*)d_ws;                          // fragment-major Q
  f16* Kh  = Qf + n2;                             // row-major K
  f16* Xh  = useXh ? (Kh + n2) : nullptr;         // f16 copy of X (for gemv)
  f16* Wqh = useXh ? (Xh + n2) : (Kh + n2);       // f16 weights (dead after proj)
  f16* Wkh = Wqh + (size_t)DD * DD;
  float* pz    = (float*)Wqh;                     // alias after proj reads
  float* sdg   = pz + 6 * (size_t)MM;
  float* wdiag = sdg + MM;

  cvt2_f32_f16<<<576, 256, 0, stream>>>(Wq_w, Wk_w, Wqh, Wkh, DD * DD);

  proj_qk<<<dim3(512, 3, 2), 256, 0, stream>>>(X, Wqh, Wkh, Wq_b, Wk_b,
                                               Qf, Kh, Xh);

  attn16<<<768, 256, 0, stream>>>(Qf, Kh, mask, pz, sdg);

  merge6<<<128, 256, 0, stream>>>(pz, sdg, wdiag, out);

  if (useXh)
    out_gemv_h<<<dim3(16, 3, 8), 256, 0, stream>>>(Xh, wdiag, out);
  else
    out_gemv<<<dim3(16, 3, 8), 256, 0, stream>>>(X, wdiag, out);
}

// Round 21
// 405.064 us; speedup vs baseline: 1.2198x; 1.2198x over previous
//
#include <hip/hip_runtime.h>

#define BB 8
#define TT 4096
#define DD 768
#define MM (BB*TT)   // 32768

typedef _Float16 f16;
typedef _Float16 f16x8 __attribute__((ext_vector_type(8)));
typedef float f32x4 __attribute__((ext_vector_type(4)));

typedef __attribute__((address_space(1))) void void_g;
typedef __attribute__((address_space(3))) void void_l;

// async global->LDS, 16B per lane. LDS dest = wave-uniform base + lane*16 (linear).
__device__ __forceinline__ void gload16(const void* g, void* l) {
  __builtin_amdgcn_global_load_lds((void_g*)g, (void_l*)l, 16, 0, 0);
}

// ---------------- both weight matrices f32 -> f16, one launch -------------
__global__ void cvt2_f32_f16(const float* __restrict__ a, const float* __restrict__ b,
                             f16* __restrict__ oa, f16* __restrict__ ob, int n) {
  int i = (blockIdx.x * blockDim.x + threadIdx.x) * 8;
  if (i >= 2 * n) return;
  const float* src = (i < n) ? a : b;
  f16* dst = (i < n) ? oa : ob;
  const int j = (i < n) ? i : i - n;
  float4 x = *(const float4*)(src + j);
  float4 y = *(const float4*)(src + j + 4);
  f16x8 o;
  o[0] = (f16)x.x; o[1] = (f16)x.y; o[2] = (f16)x.z; o[3] = (f16)x.w;
  o[4] = (f16)y.x; o[5] = (f16)y.y; o[6] = (f16)y.z; o[7] = (f16)y.w;
  *(f16x8*)(dst + j) = o;
}

// ---------------- fused proj dispatch: z=0 -> Q (frag layout), z=1 -> K ----
// Tile 64m x 256n (grid 512 x 3 x 2), 4 waves (1m x 4n), double-buffered
// (stage k+1 while computing k, ONE barrier/iter). LDS 40KB, 3 blocks/CU.
// Q path also writes Xh (f16 X) when n0==0. Qf fragment layout:
// idx = (((row>>6)*24 + (col>>5))*4 + ((row>>4)&3))*512
//       + ((row&15) + ((col>>3)&3)*16)*8 + (col&7)
__global__ __launch_bounds__(256, 3)
void proj_qk(const float* __restrict__ Af,
             const f16* __restrict__ Wqh, const f16* __restrict__ Wkh,
             const float* __restrict__ bq, const float* __restrict__ bk,
             f16* __restrict__ Qf, f16* __restrict__ Kh,
             f16* __restrict__ Xout) {
  __shared__ f16 As[2][64 * 32];
  __shared__ f16 Ws[2][256 * 32];
  const int isK = blockIdx.z;
  const f16* Wh = isK ? Wkh : Wqh;
  const float* bias = isK ? bk : bq;
  const int m0 = blockIdx.x * 64;
  const int n0 = blockIdx.y * 256;
  const int t = threadIdx.x;
  const int lane = t & 63;
  const int w = t >> 6;
  const int wn = w * 64;
  const int fr = lane & 15, fq = lane >> 4;
  const int xst = ((t >> 3) & 3) << 3;
  const int xrd = ((fr >> 1) & 3) << 3;

  f32x4 acc[4][4] = {};

  const int r0 = t >> 2, cA = (t & 3) * 8;
  const int e0 = t * 8;
  const int c8 = ((t & 3) ^ ((t >> 3) & 3)) * 8;
  const f16* w0 = Wh + (size_t)(n0 + r0) * DD + c8;
  const bool wout = (Xout != nullptr) && (!isK) && (n0 == 0);

#define PSTAGE(bf, ks_) do { \
    const int k0_ = (ks_) * 32; \
    gload16(w0 + k0_,                      &Ws[bf][w * 512]); \
    gload16(w0 + (size_t)64  * DD + k0_,   &Ws[bf][2048 + w * 512]); \
    gload16(w0 + (size_t)128 * DD + k0_,   &Ws[bf][4096 + w * 512]); \
    gload16(w0 + (size_t)192 * DD + k0_,   &Ws[bf][6144 + w * 512]); \
    { \
      const float* g0 = Af + (size_t)(m0 + r0) * DD + k0_ + cA; \
      float4 x0 = *(const float4*)g0, x1 = *(const float4*)(g0 + 4); \
      f16x8 va; \
      va[0] = (f16)x0.x; va[1] = (f16)x0.y; va[2] = (f16)x0.z; va[3] = (f16)x0.w; \
      va[4] = (f16)x1.x; va[5] = (f16)x1.y; va[6] = (f16)x1.z; va[7] = (f16)x1.w; \
      *(f16x8*)&As[bf][e0 ^ xst] = va; \
      if (wout) *(f16x8*)&Xout[(size_t)(m0 + r0) * DD + k0_ + cA] = va; \
    } \
  } while (0)

  PSTAGE(0, 0);
  __syncthreads();

  for (int ks = 0; ks < 24; ++ks) {
    const int bf = ks & 1;
    if (ks + 1 < 24) PSTAGE(bf ^ 1, ks + 1);
    f16x8 a[4], b[4];
#pragma unroll
    for (int i = 0; i < 4; ++i)
      a[i] = *(const f16x8*)&As[bf][(((i * 16 + fr) * 32) + fq * 8) ^ xrd];
#pragma unroll
    for (int j = 0; j < 4; ++j)
      b[j] = *(const f16x8*)&Ws[bf][(((wn + j * 16 + fr) * 32) + fq * 8) ^ xrd];
#pragma unroll
    for (int i = 0; i < 4; ++i)
#pragma unroll
      for (int j = 0; j < 4; ++j)
        acc[i][j] = __builtin_amdgcn_mfma_f32_16x16x32_f16(a[i], b[j], acc[i][j], 0, 0, 0);
    __syncthreads();
  }
#undef PSTAGE

#pragma unroll
  for (int j = 0; j < 4; ++j) {
    const int col = n0 + wn + j * 16 + fr;
    const float bv = bias[col];
#pragma unroll
    for (int i = 0; i < 4; ++i) {
#pragma unroll
      for (int r = 0; r < 4; ++r) {
        const int row = m0 + i * 16 + fq * 4 + r;
        const f16 v = (f16)(acc[i][j][r] + bv);
        if (!isK) {
          const size_t idx = (((size_t)(row >> 6) * 24 + (col >> 5)) * 4 +
                              ((row >> 4) & 3)) * 512 +
                             ((row & 15) + (((col >> 3) & 3) << 4)) * 8 + (col & 7);
          Qf[idx] = v;
        } else {
          Kh[(size_t)row * DD + col] = v;
        }
      }
    }
  }
}

// ---------------- attn15: structural-floor kernel (238us, reverted) -------
// K-step-64 phases, one-sub-ahead Q prefetch, dbuf 32KB LDS, no-max Z,
// setprio around MFMA. (256,3). Grid 768: bid = qs*24 + kh*8 + bb.
// NOTE: this decomposition's floor -- probed null/neg from all directions:
// 8-phase(R5), counted-vmcnt(R15), barrier-halving(R17), occupancy up
// (R10/R14 spill wall: 64 AGPR + Q-stream needs >128 regs), setprio(R18),
// barrier-free per-wave(R20, -47%).
__global__ __launch_bounds__(256, 3)
void attn15(const f16* __restrict__ Qf, const f16* __restrict__ K,
            const int* __restrict__ mask, float* __restrict__ pzv,
            float* __restrict__ sdg) {
  __shared__ f16 Ks[2][128 * 64];

  const int bid = blockIdx.x;
  const int qs = bid / 24;
  const int kh = (bid % 24) >> 3;
  const int bb = bid & 7;
  const int t = threadIdx.x, l = t & 63, w = t >> 6;
  const int wq = w >> 1, wk = w & 1;
  const int fr = l & 15, fq = l >> 4;
  const int q0 = qs * 128;
  const float scale = 0.036084391824351613f;  // 1/sqrt(768)
  const int lo = kh * 11;
  const int cnt = (kh < 2) ? 11 : 10;
  const int P = cnt * 12;

  const f16* Kg = K + (size_t)bb * TT * DD;

  const int grp = bb * 64 + qs * 2 + wq;
  const f16* qf = Qf + (size_t)grp * 24 * 4 * 512 + (size_t)l * 8;

  const int c8 = ((t & 3) ^ ((t >> 3) & 3)) * 8;
  const f16* klo = Kg + (size_t)(t >> 2) * DD + c8;
  const f16* khi = klo + (size_t)64 * DD;

  const int sx = (fq ^ ((fr >> 1) & 3)) * 8;
  const int bbase = (wk * 64 + fr) * 32 + sx;

  f32x4 acc[4][4] = {};
  f32x4 zacc[4] = {};
  int im0 = 1, im1 = 1, im2 = 1, im3 = 1;
  f16x8 avA[4], avB[4];

#define STAGE(bf, p_) do { \
    const size_t o0 = (size_t)(lo + (p_) / 12) * 128 * DD + (size_t)(((p_) % 12) * 64); \
    gload16(klo + o0,      &Ks[bf][w * 512]); \
    gload16(khi + o0,      &Ks[bf][2048 + w * 512]); \
    gload16(klo + o0 + 32, &Ks[bf][4096 + w * 512]); \
    gload16(khi + o0 + 32, &Ks[bf][6144 + w * 512]); \
  } while (0)

#define QLOAD(dst, dc_) do { \
    const f16* qp_ = qf + (size_t)(dc_) * 2048; \
    _Pragma("unroll") \
    for (int i = 0; i < 4; ++i) (dst)[i] = *(const f16x8*)(qp_ + i * 512); \
  } while (0)

#define MFMA_ALL(av_, bufv, off_) do { \
    f16x8 bv[4]; \
    _Pragma("unroll") \
    for (int j = 0; j < 4; ++j) bv[j] = *(const f16x8*)&Ks[bufv][(off_) + bbase + j * 512]; \
    __builtin_amdgcn_s_setprio(1); \
    _Pragma("unroll") \
    for (int i = 0; i < 4; ++i) \
      _Pragma("unroll") \
      for (int j = 0; j < 4; ++j) \
        acc[i][j] = __builtin_amdgcn_mfma_f32_16x16x32_f16((av_)[i], bv[j], acc[i][j], 0, 0, 0); \
    __builtin_amdgcn_s_setprio(0); \
  } while (0)

#define KT_EPILOGUE(kt_) do { \
    const float mb0 = im0 ? 0.f : -1e30f; \
    const float mb1 = im1 ? 0.f : -1e30f; \
    const float mb2 = im2 ? 0.f : -1e30f; \
    const float mb3 = im3 ? 0.f : -1e30f; \
    const bool isdiag = ((kt_) == qs); \
    _Pragma("unroll") \
    for (int i = 0; i < 4; ++i) { \
      _Pragma("unroll") \
      for (int rg = 0; rg < 4; ++rg) { \
        float v0 = fmaf(acc[i][0][rg], scale, mb0); \
        float v1 = fmaf(acc[i][1][rg], scale, mb1); \
        float v2 = fmaf(acc[i][2][rg], scale, mb2); \
        float v3 = fmaf(acc[i][3][rg], scale, mb3); \
        if (isdiag) { \
          const int rl = wq * 64 + i * 16 + fq * 4 + rg; \
          const int cl = wk * 64 + fr; \
          if (cl      == rl) sdg[(size_t)bb * TT + q0 + rl] = v0; \
          if (cl + 16 == rl) sdg[(size_t)bb * TT + q0 + rl] = v1; \
          if (cl + 32 == rl) sdg[(size_t)bb * TT + q0 + rl] = v2; \
          if (cl + 48 == rl) sdg[(size_t)bb * TT + q0 + rl] = v3; \
        } \
        zacc[i][rg] += __expf(v0) + __expf(v1) + __expf(v2) + __expf(v3); \
      } \
    } \
    _Pragma("unroll") \
    for (int i = 0; i < 4; ++i) \
      _Pragma("unroll") \
      for (int j = 0; j < 4; ++j) acc[i][j] = (f32x4)(0.f); \
  } while (0)

  STAGE(0, 0);
  QLOAD(avA, 0);
  __syncthreads();

  for (int p = 0; p < P; ++p) {
    const int buf = p & 1;
    const int kt = lo + p / 12, c = p % 12;
    if (c == 0) {
      const int kb = bb * TT + kt * 128 + wk * 64 + fr;
      im0 = mask[kb]; im1 = mask[kb + 16]; im2 = mask[kb + 32]; im3 = mask[kb + 48];
    }

    QLOAD(avB, 2 * c + 1);
    if (p + 1 < P) STAGE(buf ^ 1, p + 1);
    MFMA_ALL(avA, buf, 0);

    if (p + 1 < P) QLOAD(avA, 2 * (((p + 1) % 12)));
    MFMA_ALL(avB, buf, 4096);

    if (c == 11) KT_EPILOGUE(kt);

    __syncthreads();
  }
#undef STAGE
#undef QLOAD
#undef MFMA_ALL
#undef KT_EPILOGUE

  const int slot = kh * 2 + wk;
#pragma unroll
  for (int i = 0; i < 4; ++i) {
#pragma unroll
    for (int rg = 0; rg < 4; ++rg) {
      float z = zacc[i][rg];
#pragma unroll
      for (int off = 1; off < 16; off <<= 1) z += __shfl_xor(z, off);
      if (fr == 0) {
        const int row = wq * 64 + i * 16 + fq * 4 + rg;
        pzv[(size_t)slot * MM + bb * TT + q0 + row] = z;
      }
    }
  }
}

// ---------------- merge 6 partials -> wdiag (+ zero out) ----------------
__global__ void merge6(const float* __restrict__ pz, const float* __restrict__ sdg,
                       float* __restrict__ wdiag, float* __restrict__ out) {
  int i = blockIdx.x * 256 + threadIdx.x;
  if (i < BB * DD) out[i] = 0.f;
  if (i >= MM) return;
  float Z = 0.f;
#pragma unroll
  for (int s = 0; s < 6; ++s) Z += pz[(size_t)s * MM + i];
  wdiag[i] = __expf(sdg[i]) / Z;
}

// out[b,d] = sum_t X[b,t,d] * wdiag[b,t]  (f32 X fallback)
__global__ __launch_bounds__(256)
void out_gemv(const float* __restrict__ X, const float* __restrict__ wdiag,
              float* __restrict__ out) {
  __shared__ float wsm[256];
  const int b = blockIdx.z;
  const int d = blockIdx.y * 256 + threadIdx.x;
  const int tbase = blockIdx.x * 256;
  wsm[threadIdx.x] = wdiag[b * TT + tbase + threadIdx.x];
  __syncthreads();
  float acc = 0.f;
  const float* xp = X + (size_t)(b * TT + tbase) * DD + d;
#pragma unroll 4
  for (int i = 0; i < 256; ++i) acc += xp[(size_t)i * DD] * wsm[i];
  atomicAdd(&out[b * DD + d], acc);
}

// out[b,d] = sum_t Xh[b,t,d] * wdiag[b,t]  (f16 X, half the traffic)
__global__ __launch_bounds__(256)
void out_gemv_h(const f16* __restrict__ Xh, const float* __restrict__ wdiag,
                float* __restrict__ out) {
  __shared__ float wsm[256];
  const int b = blockIdx.z;
  const int d = blockIdx.y * 256 + threadIdx.x;
  const int tbase = blockIdx.x * 256;
  wsm[threadIdx.x] = wdiag[b * TT + tbase + threadIdx.x];
  __syncthreads();
  float acc = 0.f;
  const f16* xp = Xh + (size_t)(b * TT + tbase) * DD + d;
#pragma unroll 4
  for (int i = 0; i < 256; ++i) acc += (float)xp[(size_t)i * DD] * wsm[i];
  atomicAdd(&out[b * DD + d], acc);
}

extern "C" void kernel_launch(void* const* d_in, const int* in_sizes, int n_in,
                              void* d_out, int out_size, void* d_ws, size_t ws_size,
                              hipStream_t stream) {
  const float* X    = (const float*)d_in[0];
  const int*   mask = (const int*)d_in[1];
  const float* Wq_w = (const float*)d_in[2];
  const float* Wq_b = (const float*)d_in[3];
  const float* Wk_w = (const float*)d_in[4];
  const float* Wk_b = (const float*)d_in[5];
  float* out = (float*)d_out;

  const size_t n2 = (size_t)MM * DD;              // 25.17M f16 elems
  const size_t wreg = 2 * (size_t)DD * DD;
  const size_t need_full = (3 * n2 + wreg) * sizeof(f16);  // ~153.4 MB
  const bool useXh = ws_size >= need_full;

  f16* Qf  = (f16*)d_ws;                          // fragment-major Q
  f16* Kh  = Qf + n2;                             // row-major K
  f16* Xh  = useXh ? (Kh + n2) : nullptr;         // f16 copy of X (for gemv)
  f16* Wqh = useXh ? (Xh + n2) : (Kh + n2);       // f16 weights (dead after proj)
  f16* Wkh = Wqh + (size_t)DD * DD;
  float* pz    = (float*)Wqh;                     // alias after proj reads
  float* sdg   = pz + 6 * (size_t)MM;
  float* wdiag = sdg + MM;

  cvt2_f32_f16<<<576, 256, 0, stream>>>(Wq_w, Wk_w, Wqh, Wkh, DD * DD);

  proj_qk<<<dim3(512, 3, 2), 256, 0, stream>>>(X, Wqh, Wkh, Wq_b, Wk_b,
                                               Qf, Kh, Xh);

  attn15<<<768, 256, 0, stream>>>(Qf, Kh, mask, pz, sdg);

  merge6<<<128, 256, 0, stream>>>(pz, sdg, wdiag, out);

  if (useXh)
    out_gemv_h<<<dim3(16, 3, 8), 256, 0, stream>>>(Xh, wdiag, out);
  else
    out_gemv<<<dim3(16, 3, 8), 256, 0, stream>>>(X, wdiag, out);
}

// Round 22
// 241.717 us; speedup vs baseline: 2.0441x; 1.6758x over previous
//
#include <hip/hip_runtime.h>

#define BB 8
#define TT 4096
#define DD 768
#define MM (BB*TT)   // 32768

typedef _Float16 f16;
typedef _Float16 f16x8 __attribute__((ext_vector_type(8)));
typedef float f32x4 __attribute__((ext_vector_type(4)));

typedef __attribute__((address_space(1))) void void_g;
typedef __attribute__((address_space(3))) void void_l;

// async global->LDS, 16B per lane. LDS dest = wave-uniform base + lane*16 (linear).
__device__ __forceinline__ void gload16(const void* g, void* l) {
  __builtin_amdgcn_global_load_lds((void_g*)g, (void_l*)l, 16, 0, 0);
}

// ---------------- both weight matrices f32 -> f16, one launch -------------
__global__ void cvt2_f32_f16(const float* __restrict__ a, const float* __restrict__ b,
                             f16* __restrict__ oa, f16* __restrict__ ob, int n) {
  int i = (blockIdx.x * blockDim.x + threadIdx.x) * 8;
  if (i >= 2 * n) return;
  const float* src = (i < n) ? a : b;
  f16* dst = (i < n) ? oa : ob;
  const int j = (i < n) ? i : i - n;
  float4 x = *(const float4*)(src + j);
  float4 y = *(const float4*)(src + j + 4);
  f16x8 o;
  o[0] = (f16)x.x; o[1] = (f16)x.y; o[2] = (f16)x.z; o[3] = (f16)x.w;
  o[4] = (f16)y.x; o[5] = (f16)y.y; o[6] = (f16)y.z; o[7] = (f16)y.w;
  *(f16x8*)(dst + j) = o;
}

// ---------------- mask compaction: idx[j]->t, nb[b]; zero wdiag at masked --
// One block per batch, 4 waves x 1024 elems; ballot/popcount prefix.
__global__ __launch_bounds__(256)
void compact_mask(const int* __restrict__ mask, int* __restrict__ idx,
                  int* __restrict__ nbv, float* __restrict__ wdiag) {
  __shared__ int wcnt[4];
  const int b = blockIdx.x;
  const int w = threadIdx.x >> 6, l = threadIdx.x & 63;
  const int* mb = mask + b * TT + w * 1024;
  int mv[16];
  unsigned long long bal[16];
#pragma unroll
  for (int c = 0; c < 16; ++c) {
    mv[c] = mb[c * 64 + l];
    bal[c] = __ballot(mv[c] != 0);
    if (!mv[c]) wdiag[b * TT + w * 1024 + c * 64 + l] = 0.f;
  }
  int tot = 0;
#pragma unroll
  for (int c = 0; c < 16; ++c) tot += __popcll(bal[c]);
  if (l == 0) wcnt[w] = tot;
  __syncthreads();
  int base = 0;
  for (int ww = 0; ww < w; ++ww) base += wcnt[ww];
#pragma unroll
  for (int c = 0; c < 16; ++c) {
    const int pre = __popcll(bal[c] & ((1ull << l) - 1ull));
    if (mv[c]) idx[b * TT + base + pre] = w * 1024 + c * 64 + l;
    base += __popcll(bal[c]);
  }
  if (w == 3 && l == 0) nbv[b] = base;
}

// ---------------- compacted proj: z=0 -> Q (frag layout), z=1 -> K --------
// Tile 64m x 256n per batch (grid (8*64) x 3 x 2), compacted rows via idx
// gather (row-contiguous reads). Early-exit beyond ceil(nb/64). Outputs are
// per-batch compacted: Qf frag layout (within-batch rows), Kh row-major.
// Q path writes Xh at ORIGINAL row t (for gemv) when n0==0.
__global__ __launch_bounds__(256, 3)
void proj_qkc(const float* __restrict__ Af,
              const f16* __restrict__ Wqh, const f16* __restrict__ Wkh,
              const float* __restrict__ bq, const float* __restrict__ bk,
              const int* __restrict__ idx, const int* __restrict__ nbv,
              f16* __restrict__ Qf, f16* __restrict__ Kh,
              f16* __restrict__ Xout) {
  const int b  = blockIdx.x >> 6;
  const int m0 = (blockIdx.x & 63) * 64;   // compacted row base within batch
  const int nb = nbv[b];
  if (m0 >= ((nb + 63) & ~63)) return;

  __shared__ f16 As[2][64 * 32];
  __shared__ f16 Ws[2][256 * 32];
  const int isK = blockIdx.z;
  const f16* Wh = isK ? Wkh : Wqh;
  const float* bias = isK ? bk : bq;
  const int n0 = blockIdx.y * 256;
  const int t = threadIdx.x;
  const int lane = t & 63;
  const int w = t >> 6;
  const int wn = w * 64;
  const int fr = lane & 15, fq = lane >> 4;
  const int xst = ((t >> 3) & 3) << 3;
  const int xrd = ((fr >> 1) & 3) << 3;

  f32x4 acc[4][4] = {};

  const int r0 = t >> 2, cA = (t & 3) * 8;
  const int e0 = t * 8;
  const int c8 = ((t & 3) ^ ((t >> 3) & 3)) * 8;
  const f16* w0 = Wh + (size_t)(n0 + r0) * DD + c8;

  const int ja = m0 + r0;
  const int tA = idx[b * TT + (ja < nb ? ja : nb - 1)];
  const float* arow = Af + ((size_t)b * TT + tA) * DD + cA;
  f16* xrow = (Xout != nullptr) ? Xout + ((size_t)b * TT + tA) * DD + cA : nullptr;
  const bool wout = (Xout != nullptr) && (!isK) && (n0 == 0);

#define PSTAGE(bf, ks_) do { \
    const int k0_ = (ks_) * 32; \
    gload16(w0 + k0_,                      &Ws[bf][w * 512]); \
    gload16(w0 + (size_t)64  * DD + k0_,   &Ws[bf][2048 + w * 512]); \
    gload16(w0 + (size_t)128 * DD + k0_,   &Ws[bf][4096 + w * 512]); \
    gload16(w0 + (size_t)192 * DD + k0_,   &Ws[bf][6144 + w * 512]); \
    { \
      const float* g0 = arow + k0_; \
      float4 x0 = *(const float4*)g0, x1 = *(const float4*)(g0 + 4); \
      f16x8 va; \
      va[0] = (f16)x0.x; va[1] = (f16)x0.y; va[2] = (f16)x0.z; va[3] = (f16)x0.w; \
      va[4] = (f16)x1.x; va[5] = (f16)x1.y; va[6] = (f16)x1.z; va[7] = (f16)x1.w; \
      *(f16x8*)&As[bf][e0 ^ xst] = va; \
      if (wout) *(f16x8*)(xrow + k0_) = va; \
    } \
  } while (0)

  PSTAGE(0, 0);
  __syncthreads();

  for (int ks = 0; ks < 24; ++ks) {
    const int bf = ks & 1;
    if (ks + 1 < 24) PSTAGE(bf ^ 1, ks + 1);
    f16x8 a[4], bfr[4];
#pragma unroll
    for (int i = 0; i < 4; ++i)
      a[i] = *(const f16x8*)&As[bf][(((i * 16 + fr) * 32) + fq * 8) ^ xrd];
#pragma unroll
    for (int j = 0; j < 4; ++j)
      bfr[j] = *(const f16x8*)&Ws[bf][(((wn + j * 16 + fr) * 32) + fq * 8) ^ xrd];
#pragma unroll
    for (int i = 0; i < 4; ++i)
#pragma unroll
      for (int j = 0; j < 4; ++j)
        acc[i][j] = __builtin_amdgcn_mfma_f32_16x16x32_f16(a[i], bfr[j], acc[i][j], 0, 0, 0);
    __syncthreads();
  }
#undef PSTAGE

#pragma unroll
  for (int j = 0; j < 4; ++j) {
    const int col = n0 + wn + j * 16 + fr;
    const float bv = bias[col];
#pragma unroll
    for (int i = 0; i < 4; ++i) {
#pragma unroll
      for (int r = 0; r < 4; ++r) {
        const int rowc = m0 + i * 16 + fq * 4 + r;   // compacted within batch
        const f16 v = (f16)(acc[i][j][r] + bv);
        if (!isK) {
          const size_t q = (size_t)b * TT * DD +
              ((((size_t)(rowc >> 6) * 24 + (col >> 5)) * 4 + ((rowc >> 4) & 3)) * 512 +
               ((rowc & 15) + (((col >> 3) & 3) << 4)) * 8 + (col & 7));
          Qf[q] = v;
        } else {
          Kh[(size_t)b * TT * DD + (size_t)rowc * DD + col] = v;
        }
      }
    }
  }
}

// ---------------- attn17: attn15 structure over COMPACTED rows/cols -------
// Per-batch compacted ranges; kh SIXTHS (grid 1536, active ~768 = 3/CU).
// Validity = (col < nb), computed arithmetically (no mask loads). 12 pz slots.
__global__ __launch_bounds__(256, 3)
void attn17(const f16* __restrict__ Qf, const f16* __restrict__ K,
            const int* __restrict__ nbv, float* __restrict__ pzv,
            float* __restrict__ sdg) {
  const int bid = blockIdx.x;
  const int qs = bid / 48;
  const int rem = bid % 48;
  const int kh = rem >> 3;
  const int bb = rem & 7;
  const int nb = nbv[bb];
  if (qs * 128 >= nb) return;

  __shared__ f16 Ks[2][128 * 64];
  const int t = threadIdx.x, l = t & 63, w = t >> 6;
  const int wq = w >> 1, wk = w & 1;
  const int fr = l & 15, fq = l >> 4;
  const int q0 = qs * 128;
  const float scale = 0.036084391824351613f;  // 1/sqrt(768)
  const int nkt = (nb + 127) >> 7;
  const int q6 = nkt / 6, r6 = nkt % 6;
  const int cnt = q6 + (kh < r6 ? 1 : 0);
  const int lo  = kh * q6 + (kh < r6 ? kh : r6);
  const int P = cnt * 12;

  const f16* Kg = K + (size_t)bb * TT * DD;
  const f16* qf = Qf + (size_t)bb * TT * DD + (size_t)(qs * 2 + wq) * 49152 + (size_t)l * 8;

  const int c8 = ((t & 3) ^ ((t >> 3) & 3)) * 8;
  const f16* klo = Kg + (size_t)(t >> 2) * DD + c8;
  const f16* khi = klo + (size_t)64 * DD;

  const int sx = (fq ^ ((fr >> 1) & 3)) * 8;
  const int bbase = (wk * 64 + fr) * 32 + sx;

  f32x4 acc[4][4] = {};
  f32x4 zacc[4] = {};
  int im0 = 0, im1 = 0, im2 = 0, im3 = 0;
  f16x8 avA[4], avB[4];

#define STAGE(bf, p_) do { \
    const size_t o0 = (size_t)(lo + (p_) / 12) * 128 * DD + (size_t)(((p_) % 12) * 64); \
    gload16(klo + o0,      &Ks[bf][w * 512]); \
    gload16(khi + o0,      &Ks[bf][2048 + w * 512]); \
    gload16(klo + o0 + 32, &Ks[bf][4096 + w * 512]); \
    gload16(khi + o0 + 32, &Ks[bf][6144 + w * 512]); \
  } while (0)

#define QLOAD(dst, dc_) do { \
    const f16* qp_ = qf + (size_t)(dc_) * 2048; \
    _Pragma("unroll") \
    for (int i = 0; i < 4; ++i) (dst)[i] = *(const f16x8*)(qp_ + i * 512); \
  } while (0)

#define MFMA_ALL(av_, bufv, off_) do { \
    f16x8 bv[4]; \
    _Pragma("unroll") \
    for (int j = 0; j < 4; ++j) bv[j] = *(const f16x8*)&Ks[bufv][(off_) + bbase + j * 512]; \
    __builtin_amdgcn_s_setprio(1); \
    _Pragma("unroll") \
    for (int i = 0; i < 4; ++i) \
      _Pragma("unroll") \
      for (int j = 0; j < 4; ++j) \
        acc[i][j] = __builtin_amdgcn_mfma_f32_16x16x32_f16((av_)[i], bv[j], acc[i][j], 0, 0, 0); \
    __builtin_amdgcn_s_setprio(0); \
  } while (0)

#define KT_EPILOGUE(kt_) do { \
    const float mb0 = im0 ? 0.f : -1e30f; \
    const float mb1 = im1 ? 0.f : -1e30f; \
    const float mb2 = im2 ? 0.f : -1e30f; \
    const float mb3 = im3 ? 0.f : -1e30f; \
    const bool isdiag = ((kt_) == qs); \
    _Pragma("unroll") \
    for (int i = 0; i < 4; ++i) { \
      _Pragma("unroll") \
      for (int rg = 0; rg < 4; ++rg) { \
        float v0 = fmaf(acc[i][0][rg], scale, mb0); \
        float v1 = fmaf(acc[i][1][rg], scale, mb1); \
        float v2 = fmaf(acc[i][2][rg], scale, mb2); \
        float v3 = fmaf(acc[i][3][rg], scale, mb3); \
        if (isdiag) { \
          const int rl = wq * 64 + i * 16 + fq * 4 + rg; \
          const int cl = wk * 64 + fr; \
          if (cl      == rl) sdg[(size_t)bb * TT + q0 + rl] = v0; \
          if (cl + 16 == rl) sdg[(size_t)bb * TT + q0 + rl] = v1; \
          if (cl + 32 == rl) sdg[(size_t)bb * TT + q0 + rl] = v2; \
          if (cl + 48 == rl) sdg[(size_t)bb * TT + q0 + rl] = v3; \
        } \
        zacc[i][rg] += __expf(v0) + __expf(v1) + __expf(v2) + __expf(v3); \
      } \
    } \
    _Pragma("unroll") \
    for (int i = 0; i < 4; ++i) \
      _Pragma("unroll") \
      for (int j = 0; j < 4; ++j) acc[i][j] = (f32x4)(0.f); \
  } while (0)

  STAGE(0, 0);
  QLOAD(avA, 0);
  __syncthreads();

  for (int p = 0; p < P; ++p) {
    const int buf = p & 1;
    const int kt = lo + p / 12, c = p % 12;
    if (c == 0) {  // column validity for this kt (arithmetic, no loads)
      const int cb0 = kt * 128 + wk * 64 + fr;
      im0 = (cb0 < nb); im1 = (cb0 + 16 < nb);
      im2 = (cb0 + 32 < nb); im3 = (cb0 + 48 < nb);
    }

    QLOAD(avB, 2 * c + 1);
    if (p + 1 < P) STAGE(buf ^ 1, p + 1);
    MFMA_ALL(avA, buf, 0);

    if (p + 1 < P) QLOAD(avA, 2 * (((p + 1) % 12)));
    MFMA_ALL(avB, buf, 4096);

    if (c == 11) KT_EPILOGUE(kt);

    __syncthreads();
  }
#undef STAGE
#undef QLOAD
#undef MFMA_ALL
#undef KT_EPILOGUE

  const int slot = kh * 2 + wk;     // 12 slots
#pragma unroll
  for (int i = 0; i < 4; ++i) {
#pragma unroll
    for (int rg = 0; rg < 4; ++rg) {
      float z = zacc[i][rg];
#pragma unroll
      for (int off = 1; off < 16; off <<= 1) z += __shfl_xor(z, off);
      if (fr == 0) {
        const int row = wq * 64 + i * 16 + fq * 4 + rg;
        pzv[(size_t)slot * MM + bb * TT + q0 + row] = z;
      }
    }
  }
}

// ---------------- merge 12 partials, scatter wdiag, zero out --------------
__global__ void merge12s(const float* __restrict__ pz, const float* __restrict__ sdg,
                         const int* __restrict__ idx, const int* __restrict__ nbv,
                         float* __restrict__ wdiag, float* __restrict__ out) {
  int i = blockIdx.x * 256 + threadIdx.x;
  if (i < BB * DD) out[i] = 0.f;
  if (i >= MM) return;
  const int b = i >> 12, j = i & 4095;
  if (j >= nbv[b]) return;
  float Z = 0.f;
#pragma unroll
  for (int s = 0; s < 12; ++s) Z += pz[(size_t)s * MM + i];
  wdiag[b * TT + idx[i]] = __expf(sdg[i]) / Z;
}

// =================== R19 fallback path (proven, 403us) ====================
__global__ __launch_bounds__(256, 3)
void proj_qk(const float* __restrict__ Af,
             const f16* __restrict__ Wqh, const f16* __restrict__ Wkh,
             const float* __restrict__ bq, const float* __restrict__ bk,
             f16* __restrict__ Qf, f16* __restrict__ Kh,
             f16* __restrict__ Xout) {
  __shared__ f16 As[2][64 * 32];
  __shared__ f16 Ws[2][256 * 32];
  const int isK = blockIdx.z;
  const f16* Wh = isK ? Wkh : Wqh;
  const float* bias = isK ? bk : bq;
  const int m0 = blockIdx.x * 64;
  const int n0 = blockIdx.y * 256;
  const int t = threadIdx.x;
  const int lane = t & 63;
  const int w = t >> 6;
  const int wn = w * 64;
  const int fr = lane & 15, fq = lane >> 4;
  const int xst = ((t >> 3) & 3) << 3;
  const int xrd = ((fr >> 1) & 3) << 3;
  f32x4 acc[4][4] = {};
  const int r0 = t >> 2, cA = (t & 3) * 8;
  const int e0 = t * 8;
  const int c8 = ((t & 3) ^ ((t >> 3) & 3)) * 8;
  const f16* w0 = Wh + (size_t)(n0 + r0) * DD + c8;
  const bool wout = (Xout != nullptr) && (!isK) && (n0 == 0);

#define PSTAGE(bf, ks_) do { \
    const int k0_ = (ks_) * 32; \
    gload16(w0 + k0_,                      &Ws[bf][w * 512]); \
    gload16(w0 + (size_t)64  * DD + k0_,   &Ws[bf][2048 + w * 512]); \
    gload16(w0 + (size_t)128 * DD + k0_,   &Ws[bf][4096 + w * 512]); \
    gload16(w0 + (size_t)192 * DD + k0_,   &Ws[bf][6144 + w * 512]); \
    { \
      const float* g0 = Af + (size_t)(m0 + r0) * DD + k0_ + cA; \
      float4 x0 = *(const float4*)g0, x1 = *(const float4*)(g0 + 4); \
      f16x8 va; \
      va[0] = (f16)x0.x; va[1] = (f16)x0.y; va[2] = (f16)x0.z; va[3] = (f16)x0.w; \
      va[4] = (f16)x1.x; va[5] = (f16)x1.y; va[6] = (f16)x1.z; va[7] = (f16)x1.w; \
      *(f16x8*)&As[bf][e0 ^ xst] = va; \
      if (wout) *(f16x8*)&Xout[(size_t)(m0 + r0) * DD + k0_ + cA] = va; \
    } \
  } while (0)

  PSTAGE(0, 0);
  __syncthreads();
  for (int ks = 0; ks < 24; ++ks) {
    const int bf = ks & 1;
    if (ks + 1 < 24) PSTAGE(bf ^ 1, ks + 1);
    f16x8 a[4], b[4];
#pragma unroll
    for (int i = 0; i < 4; ++i)
      a[i] = *(const f16x8*)&As[bf][(((i * 16 + fr) * 32) + fq * 8) ^ xrd];
#pragma unroll
    for (int j = 0; j < 4; ++j)
      b[j] = *(const f16x8*)&Ws[bf][(((wn + j * 16 + fr) * 32) + fq * 8) ^ xrd];
#pragma unroll
    for (int i = 0; i < 4; ++i)
#pragma unroll
      for (int j = 0; j < 4; ++j)
        acc[i][j] = __builtin_amdgcn_mfma_f32_16x16x32_f16(a[i], b[j], acc[i][j], 0, 0, 0);
    __syncthreads();
  }
#undef PSTAGE
#pragma unroll
  for (int j = 0; j < 4; ++j) {
    const int col = n0 + wn + j * 16 + fr;
    const float bv = bias[col];
#pragma unroll
    for (int i = 0; i < 4; ++i) {
#pragma unroll
      for (int r = 0; r < 4; ++r) {
        const int row = m0 + i * 16 + fq * 4 + r;
        const f16 v = (f16)(acc[i][j][r] + bv);
        if (!isK) {
          const size_t idxq = (((size_t)(row >> 6) * 24 + (col >> 5)) * 4 +
                              ((row >> 4) & 3)) * 512 +
                             ((row & 15) + (((col >> 3) & 3) << 4)) * 8 + (col & 7);
          Qf[idxq] = v;
        } else {
          Kh[(size_t)row * DD + col] = v;
        }
      }
    }
  }
}

__global__ __launch_bounds__(256, 3)
void attn15(const f16* __restrict__ Qf, const f16* __restrict__ K,
            const int* __restrict__ mask, float* __restrict__ pzv,
            float* __restrict__ sdg) {
  __shared__ f16 Ks[2][128 * 64];
  const int bid = blockIdx.x;
  const int qs = bid / 24;
  const int kh = (bid % 24) >> 3;
  const int bb = bid & 7;
  const int t = threadIdx.x, l = t & 63, w = t >> 6;
  const int wq = w >> 1, wk = w & 1;
  const int fr = l & 15, fq = l >> 4;
  const int q0 = qs * 128;
  const float scale = 0.036084391824351613f;
  const int lo = kh * 11;
  const int cnt = (kh < 2) ? 11 : 10;
  const int P = cnt * 12;
  const f16* Kg = K + (size_t)bb * TT * DD;
  const int grp = bb * 64 + qs * 2 + wq;
  const f16* qf = Qf + (size_t)grp * 24 * 4 * 512 + (size_t)l * 8;
  const int c8 = ((t & 3) ^ ((t >> 3) & 3)) * 8;
  const f16* klo = Kg + (size_t)(t >> 2) * DD + c8;
  const f16* khi = klo + (size_t)64 * DD;
  const int sx = (fq ^ ((fr >> 1) & 3)) * 8;
  const int bbase = (wk * 64 + fr) * 32 + sx;
  f32x4 acc[4][4] = {};
  f32x4 zacc[4] = {};
  int im0 = 1, im1 = 1, im2 = 1, im3 = 1;
  f16x8 avA[4], avB[4];

#define STAGE(bf, p_) do { \
    const size_t o0 = (size_t)(lo + (p_) / 12) * 128 * DD + (size_t)(((p_) % 12) * 64); \
    gload16(klo + o0,      &Ks[bf][w * 512]); \
    gload16(khi + o0,      &Ks[bf][2048 + w * 512]); \
    gload16(klo + o0 + 32, &Ks[bf][4096 + w * 512]); \
    gload16(khi + o0 + 32, &Ks[bf][6144 + w * 512]); \
  } while (0)
#define QLOAD(dst, dc_) do { \
    const f16* qp_ = qf + (size_t)(dc_) * 2048; \
    _Pragma("unroll") \
    for (int i = 0; i < 4; ++i) (dst)[i] = *(const f16x8*)(qp_ + i * 512); \
  } while (0)
#define MFMA_ALL(av_, bufv, off_) do { \
    f16x8 bv[4]; \
    _Pragma("unroll") \
    for (int j = 0; j < 4; ++j) bv[j] = *(const f16x8*)&Ks[bufv][(off_) + bbase + j * 512]; \
    __builtin_amdgcn_s_setprio(1); \
    _Pragma("unroll") \
    for (int i = 0; i < 4; ++i) \
      _Pragma("unroll") \
      for (int j = 0; j < 4; ++j) \
        acc[i][j] = __builtin_amdgcn_mfma_f32_16x16x32_f16((av_)[i], bv[j], acc[i][j], 0, 0, 0); \
    __builtin_amdgcn_s_setprio(0); \
  } while (0)
#define KT_EPILOGUE(kt_) do { \
    const float mb0 = im0 ? 0.f : -1e30f; \
    const float mb1 = im1 ? 0.f : -1e30f; \
    const float mb2 = im2 ? 0.f : -1e30f; \
    const float mb3 = im3 ? 0.f : -1e30f; \
    const bool isdiag = ((kt_) == qs); \
    _Pragma("unroll") \
    for (int i = 0; i < 4; ++i) { \
      _Pragma("unroll") \
      for (int rg = 0; rg < 4; ++rg) { \
        float v0 = fmaf(acc[i][0][rg], scale, mb0); \
        float v1 = fmaf(acc[i][1][rg], scale, mb1); \
        float v2 = fmaf(acc[i][2][rg], scale, mb2); \
        float v3 = fmaf(acc[i][3][rg], scale, mb3); \
        if (isdiag) { \
          const int rl = wq * 64 + i * 16 + fq * 4 + rg; \
          const int cl = wk * 64 + fr; \
          if (cl      == rl) sdg[(size_t)bb * TT + q0 + rl] = v0; \
          if (cl + 16 == rl) sdg[(size_t)bb * TT + q0 + rl] = v1; \
          if (cl + 32 == rl) sdg[(size_t)bb * TT + q0 + rl] = v2; \
          if (cl + 48 == rl) sdg[(size_t)bb * TT + q0 + rl] = v3; \
        } \
        zacc[i][rg] += __expf(v0) + __expf(v1) + __expf(v2) + __expf(v3); \
      } \
    } \
    _Pragma("unroll") \
    for (int i = 0; i < 4; ++i) \
      _Pragma("unroll") \
      for (int j = 0; j < 4; ++j) acc[i][j] = (f32x4)(0.f); \
  } while (0)

  STAGE(0, 0);
  QLOAD(avA, 0);
  __syncthreads();
  for (int p = 0; p < P; ++p) {
    const int buf = p & 1;
    const int kt = lo + p / 12, c = p % 12;
    if (c == 0) {
      const int kb = bb * TT + kt * 128 + wk * 64 + fr;
      im0 = mask[kb]; im1 = mask[kb + 16]; im2 = mask[kb + 32]; im3 = mask[kb + 48];
    }
    QLOAD(avB, 2 * c + 1);
    if (p + 1 < P) STAGE(buf ^ 1, p + 1);
    MFMA_ALL(avA, buf, 0);
    if (p + 1 < P) QLOAD(avA, 2 * (((p + 1) % 12)));
    MFMA_ALL(avB, buf, 4096);
    if (c == 11) KT_EPILOGUE(kt);
    __syncthreads();
  }
#undef STAGE
#undef QLOAD
#undef MFMA_ALL
#undef KT_EPILOGUE
  const int slot = kh * 2 + wk;
#pragma unroll
  for (int i = 0; i < 4; ++i) {
#pragma unroll
    for (int rg = 0; rg < 4; ++rg) {
      float z = zacc[i][rg];
#pragma unroll
      for (int off = 1; off < 16; off <<= 1) z += __shfl_xor(z, off);
      if (fr == 0) {
        const int row = wq * 64 + i * 16 + fq * 4 + rg;
        pzv[(size_t)slot * MM + bb * TT + q0 + row] = z;
      }
    }
  }
}

__global__ void merge6(const float* __restrict__ pz, const float* __restrict__ sdg,
                       float* __restrict__ wdiag, float* __restrict__ out) {
  int i = blockIdx.x * 256 + threadIdx.x;
  if (i < BB * DD) out[i] = 0.f;
  if (i >= MM) return;
  float Z = 0.f;
#pragma unroll
  for (int s = 0; s < 6; ++s) Z += pz[(size_t)s * MM + i];
  wdiag[i] = __expf(sdg[i]) / Z;
}

// ---------------- output gemv (shared) ----------------
__global__ __launch_bounds__(256)
void out_gemv(const float* __restrict__ X, const float* __restrict__ wdiag,
              float* __restrict__ out) {
  __shared__ float wsm[256];
  const int b = blockIdx.z;
  const int d = blockIdx.y * 256 + threadIdx.x;
  const int tbase = blockIdx.x * 256;
  wsm[threadIdx.x] = wdiag[b * TT + tbase + threadIdx.x];
  __syncthreads();
  float acc = 0.f;
  const float* xp = X + (size_t)(b * TT + tbase) * DD + d;
#pragma unroll 4
  for (int i = 0; i < 256; ++i) acc += xp[(size_t)i * DD] * wsm[i];
  atomicAdd(&out[b * DD + d], acc);
}

__global__ __launch_bounds__(256)
void out_gemv_h(const f16* __restrict__ Xh, const float* __restrict__ wdiag,
                float* __restrict__ out) {
  __shared__ float wsm[256];
  const int b = blockIdx.z;
  const int d = blockIdx.y * 256 + threadIdx.x;
  const int tbase = blockIdx.x * 256;
  wsm[threadIdx.x] = wdiag[b * TT + tbase + threadIdx.x];
  __syncthreads();
  float acc = 0.f;
  const f16* xp = Xh + (size_t)(b * TT + tbase) * DD + d;
#pragma unroll 4
  for (int i = 0; i < 256; ++i) acc += (float)xp[(size_t)i * DD] * wsm[i];
  atomicAdd(&out[b * DD + d], acc);
}

extern "C" void kernel_launch(void* const* d_in, const int* in_sizes, int n_in,
                              void* d_out, int out_size, void* d_ws, size_t ws_size,
                              hipStream_t stream) {
  const float* X    = (const float*)d_in[0];
  const int*   mask = (const int*)d_in[1];
  const float* Wq_w = (const float*)d_in[2];
  const float* Wq_b = (const float*)d_in[3];
  const float* Wk_w = (const float*)d_in[4];
  const float* Wk_b = (const float*)d_in[5];
  float* out = (float*)d_out;

  const size_t n2 = (size_t)MM * DD;      // 25.17M f16 elems
  const size_t wde = (size_t)DD * DD;

  // ---- new-path layout (~105 MB base, +50.3 MB optional Xh) ----
  char* p = (char*)d_ws;
  f16* Qf = (f16*)p;            p += n2 * sizeof(f16);
  f16* Kh = (f16*)p;            p += n2 * sizeof(f16);
  f16* Wqh = (f16*)p;           p += wde * sizeof(f16);
  f16* Wkh = (f16*)p;           p += wde * sizeof(f16);
  int* idx = (int*)p;           p += (size_t)MM * sizeof(int);
  int* nbv = (int*)p;           p += 64;
  float* pz = (float*)p;        p += (size_t)12 * MM * sizeof(float);
  float* sdg = (float*)p;       p += (size_t)MM * sizeof(float);
  float* wdiag = (float*)p;     p += (size_t)MM * sizeof(float);
  const size_t need_base = (size_t)(p - (char*)d_ws);
  f16* Xh = (f16*)p;
  const bool useNew = ws_size >= need_base;
  const bool useXh = ws_size >= need_base + n2 * sizeof(f16);

  if (useNew) {
    compact_mask<<<8, 256, 0, stream>>>(mask, idx, nbv, wdiag);
    cvt2_f32_f16<<<576, 256, 0, stream>>>(Wq_w, Wk_w, Wqh, Wkh, DD * DD);
    proj_qkc<<<dim3(512, 3, 2), 256, 0, stream>>>(X, Wqh, Wkh, Wq_b, Wk_b,
                                                  idx, nbv, Qf, Kh,
                                                  useXh ? Xh : (f16*)nullptr);
    attn17<<<1536, 256, 0, stream>>>(Qf, Kh, nbv, pz, sdg);
    merge12s<<<128, 256, 0, stream>>>(pz, sdg, idx, nbv, wdiag, out);
    if (useXh)
      out_gemv_h<<<dim3(16, 3, 8), 256, 0, stream>>>(Xh, wdiag, out);
    else
      out_gemv<<<dim3(16, 3, 8), 256, 0, stream>>>(X, wdiag, out);
  } else {
    // R19 fallback layout (~103 MB): pz/sdg/wdiag alias weights after proj
    f16* Qf2 = (f16*)d_ws;
    f16* Kh2 = Qf2 + n2;
    f16* Wqh2 = Kh2 + n2;
    f16* Wkh2 = Wqh2 + wde;
    float* pz2 = (float*)Wqh2;
    float* sdg2 = pz2 + 6 * (size_t)MM;
    float* wdiag2 = sdg2 + MM;
    cvt2_f32_f16<<<576, 256, 0, stream>>>(Wq_w, Wk_w, Wqh2, Wkh2, DD * DD);
    proj_qk<<<dim3(512, 3, 2), 256, 0, stream>>>(X, Wqh2, Wkh2, Wq_b, Wk_b,
                                                 Qf2, Kh2, (f16*)nullptr);
    attn15<<<768, 256, 0, stream>>>(Qf2, Kh2, mask, pz2, sdg2);
    merge6<<<128, 256, 0, stream>>>(pz2, sdg2, wdiag2, out);
    out_gemv<<<dim3(16, 3, 8), 256, 0, stream>>>(X, wdiag2, out);
  }
}